// Round 6
// baseline (329.882 us; speedup 1.0000x reference)
//
#include <hip/hip_runtime.h>
#include <hip/hip_bf16.h>

// CrossAttention  B=2, S=2048, D=1024, H=16, HD=64
// R16: R15 post-mortem -- halving q-rows doubled K/V load traffic and halved
// per-wave MLP (worse despite 33% occupancy). R14 mis-diagnosis corrected:
// its cap was GRID (512 blocks x 4 waves = 8 waves/CU), not registers
// (116 VGPR fits 4/SIMD). R16 keeps R14's per-wave loop EXACTLY (same MLP,
// same total load traffic) and raises residency via 8-wave blocks (512 thr):
// keys split it = w, w+8, ...; 512 blocks = 2/CU = 16 waves/CU = 4/SIMD.
// Uniform 33 chunks/block (pair 31-p,p). Combine = 3-level LDS tree (two
// sub-rounds at level 1, 34KB LDS). prep/qkv/out kernels unchanged.

#define BDIM 2
#define SDIM 2048
#define DDIM 1024
#define HDIM 16
#define HD   64
#define MDIM (BDIM*SDIM)   // 4096
// folded into Q at projection: (1/8) * log2(e)
#define C2 0.18033688011112042f

using short8  = __attribute__((ext_vector_type(8))) short;
using floatx4 = __attribute__((ext_vector_type(4))) float;

static __device__ __forceinline__ unsigned short f2bf(float x) {
    union { float f; unsigned int u; } c; c.f = x;
    unsigned int r = (c.u + 0x7fffu + ((c.u >> 16) & 1u)) >> 16;
    return (unsigned short)r;
}

// pack two fp32 -> (bf16(b)<<16)|bf16(a), round-half-up
static __device__ __forceinline__ unsigned int pack2bf(float a, float b) {
    union { float f; unsigned int u; } ua, ub;
    ua.f = a; ub.f = b;
    return __builtin_amdgcn_perm(ub.u + 0x8000u, ua.u + 0x8000u, 0x07060302u);
}

#define GLD16(g, l) __builtin_amdgcn_global_load_lds(                        \
    (const __attribute__((address_space(1))) void*)(g),                      \
    (__attribute__((address_space(3))) void*)(l), 16, 0, 0)

// ---------------- fused prep: cast x/y -> bf16 (z=0,1), wtrans (z=2..5) ----------------
__global__ __launch_bounds__(256) void prep_kernel(
    const float* __restrict__ X, const float* __restrict__ Y,
    const float* __restrict__ W0, const float* __restrict__ W1,
    const float* __restrict__ W2, const float* __restrict__ W3,
    unsigned short* __restrict__ Xo, unsigned short* __restrict__ Yo,
    unsigned short* __restrict__ T0, unsigned short* __restrict__ T1,
    unsigned short* __restrict__ T2, unsigned short* __restrict__ T3)
{
    __shared__ float tile[64][68];
    const int z = blockIdx.z;
    const int t = threadIdx.x;
    if (z < 2) {
        const float* A    = z ? Y : X;
        unsigned short* O = z ? Yo : Xo;
        const int idx = blockIdx.x * 256 + t;
        const float4 a = ((const float4*)A)[idx*2];
        const float4 b = ((const float4*)A)[idx*2 + 1];
        ushort4 lo, hi;
        lo.x = f2bf(a.x); lo.y = f2bf(a.y); lo.z = f2bf(a.z); lo.w = f2bf(a.w);
        hi.x = f2bf(b.x); hi.y = f2bf(b.y); hi.z = f2bf(b.z); hi.w = f2bf(b.w);
        ((ushort4*)O)[idx*2]     = lo;
        ((ushort4*)O)[idx*2 + 1] = hi;
        return;
    }
    if (blockIdx.x >= 256) return;
    const int zz = z - 2;
    const float* W    = (zz == 0) ? W0 : (zz == 1) ? W1 : (zz == 2) ? W2 : W3;
    unsigned short* T = (zz == 0) ? T0 : (zz == 1) ? T1 : (zz == 2) ? T2 : T3;
    const int k0 = (blockIdx.x & 15) * 64, n0 = (blockIdx.x >> 4) * 64;
    #pragma unroll
    for (int i = 0; i < 4; ++i) {
        const int idx = t + i*256;
        const int kr = idx >> 4, c4 = idx & 15;
        float4 v = *(const float4*)&W[(size_t)(k0 + kr) * DDIM + n0 + c4*4];
        tile[kr][c4*4+0] = v.x; tile[kr][c4*4+1] = v.y;
        tile[kr][c4*4+2] = v.z; tile[kr][c4*4+3] = v.w;
    }
    __syncthreads();
    #pragma unroll
    for (int i = 0; i < 4; ++i) {
        const int idx = t + i*256;
        const int nr = idx >> 4, kc = idx & 15;
        ushort4 o;
        o.x = f2bf(tile[kc*4+0][nr]); o.y = f2bf(tile[kc*4+1][nr]);
        o.z = f2bf(tile[kc*4+2][nr]); o.w = f2bf(tile[kc*4+3][nr]);
        *(ushort4*)&T[(size_t)(n0 + nr) * DDIM + k0 + kc*4] = o;
    }
}

// ---------------- 128x128 bf16 MFMA GEMM core, LDS double-buffered ----------------
template <bool SWAP>
__device__ __forceinline__ void gemm128_core(
    const unsigned short* __restrict__ A, const unsigned short* __restrict__ Bt,
    int bm, int bn, unsigned short* As, unsigned short* Bs, floatx4 acc[4][4])
{
    const int t = threadIdx.x;
    const int w = t >> 6, l = t & 63;
    const int quad = l >> 4, col = l & 15;
    const int wr = (w >> 1) * 64, wc = (w & 1) * 64;

    const int c1 = t + 256;
    const int r0 = t >> 2,  o0 = (t & 3) * 8;
    const int r1 = c1 >> 2, o1 = (c1 & 3) * 8;

    const unsigned short* Ar0 = A  + (size_t)(bm + r0) * DDIM + o0;
    const unsigned short* Ar1 = A  + (size_t)(bm + r1) * DDIM + o1;
    const unsigned short* Br0 = Bt + (size_t)(bn + r0) * DDIM + o0;
    const unsigned short* Br1 = Bt + (size_t)(bn + r1) * DDIM + o1;

    GLD16(Ar0, As + t*8);
    GLD16(Ar1, As + c1*8);
    GLD16(Br0, Bs + t*8);
    GLD16(Br1, Bs + c1*8);

    for (int kt = 0; kt < DDIM; kt += 32) {
        const int cur = (kt >> 5) & 1;
        unsigned short* Asn = As + (cur ^ 1) * 4096;
        unsigned short* Bsn = Bs + (cur ^ 1) * 4096;
        __syncthreads();
        if (kt + 32 < DDIM) {
            GLD16(Ar0 + kt + 32, Asn + t*8);
            GLD16(Ar1 + kt + 32, Asn + c1*8);
            GLD16(Br0 + kt + 32, Bsn + t*8);
            GLD16(Br1 + kt + 32, Bsn + c1*8);
        }
        const unsigned short* Asc = As + cur*4096;
        const unsigned short* Bsc = Bs + cur*4096;
        short8 af[4], bfr[4];
        #pragma unroll
        for (int i = 0; i < 4; ++i)
            af[i] = *(const short8*)&Asc[(wr + i*16 + col)*32 + quad*8];
        #pragma unroll
        for (int j = 0; j < 4; ++j)
            bfr[j] = *(const short8*)&Bsc[(wc + j*16 + col)*32 + quad*8];
        #pragma unroll
        for (int i = 0; i < 4; ++i)
            #pragma unroll
            for (int j = 0; j < 4; ++j)
                acc[i][j] = SWAP
                    ? __builtin_amdgcn_mfma_f32_16x16x32_bf16(bfr[j], af[i], acc[i][j], 0, 0, 0)
                    : __builtin_amdgcn_mfma_f32_16x16x32_bf16(af[i], bfr[j], acc[i][j], 0, 0, 0);
    }
}

// ---------------- fused Q/K/V projection (grid.z = 0/1/2) ----------------
// XCD swizzle: raw (x,y) with x in [0,8): xcd = x (lin%8). bm = x*4+(y&3),
// bn = y>>2 -> per-XCD A set = 4 tiles (1MB), W = 2MB: both L2-resident.
__global__ __launch_bounds__(256) void qkv_gemm_kernel(
    const unsigned short* __restrict__ xbf, const unsigned short* __restrict__ ybf,
    const unsigned short* __restrict__ Wqt, const unsigned short* __restrict__ Wkt,
    const unsigned short* __restrict__ Wvt,
    const float* __restrict__ bq, const float* __restrict__ bk,
    const float* __restrict__ bv,
    unsigned short* __restrict__ Qbf, unsigned short* __restrict__ Kbf,
    unsigned short* __restrict__ vT)
{
    __shared__ __align__(16) unsigned short As[2*4096];   // 16 KB
    __shared__ __align__(16) unsigned short Bs[2*4096];   // 16 KB

    const int z = blockIdx.z;
    const unsigned short* A  = (z == 0) ? xbf : ybf;
    const unsigned short* Wt = (z == 0) ? Wqt : (z == 1) ? Wkt : Wvt;
    const float* bp          = (z == 0) ? bq  : (z == 1) ? bk  : bv;

    // XCD-aware remap (grid (8,32,z)): xcd = blockIdx.x
    const int bm = (blockIdx.x * 4 + (blockIdx.y & 3)) * 128;
    const int bn = (blockIdx.y >> 2) * 128;

    const int t = threadIdx.x;
    const int w = t >> 6, l = t & 63;
    const int quad = l >> 4, col = l & 15;
    const int wr = (w >> 1) * 64, wc = (w & 1) * 64;

    floatx4 acc[4][4] = {};

    if (z < 2) {
        gemm128_core<true>(A, Wt, bm, bn, As, Bs, acc);
        unsigned short* O = (z == 0) ? Qbf : Kbf;
        const float sc = (z == 0) ? C2 : 1.0f;
        float4 bias4[4];
        #pragma unroll
        for (int j = 0; j < 4; ++j)
            bias4[j] = *(const float4*)&bp[bn + wc + j*16 + quad*4];
        #pragma unroll
        for (int i = 0; i < 4; ++i) {
            const int m = bm + wr + i*16 + col;
            unsigned short* rowp = O + (size_t)m * DDIM;
            #pragma unroll
            for (int j = 0; j < 4; ++j) {
                const float v0 = (acc[i][j][0] + bias4[j].x) * sc;
                const float v1 = (acc[i][j][1] + bias4[j].y) * sc;
                const float v2 = (acc[i][j][2] + bias4[j].z) * sc;
                const float v3 = (acc[i][j][3] + bias4[j].w) * sc;
                uint2 pk;
                pk.x = pack2bf(v0, v1);
                pk.y = pack2bf(v2, v3);
                *(uint2*)&rowp[bn + wc + j*16 + quad*4] = pk;
            }
        }
    } else {
        gemm128_core<false>(A, Wt, bm, bn, As, Bs, acc);
        #pragma unroll
        for (int j = 0; j < 4; ++j) {
            const int gn = bn + wc + j*16 + col;
            const float bias = bp[gn];
            #pragma unroll
            for (int i = 0; i < 4; ++i) {
                const int gm0 = bm + wr + i*16 + quad*4;
                uint2 pk;
                pk.x = pack2bf(acc[i][j][0] + bias, acc[i][j][1] + bias);
                pk.y = pack2bf(acc[i][j][2] + bias, acc[i][j][3] + bias);
                *(uint2*)&vT[((size_t)((gm0 >> 11) * DDIM + gn)) * SDIM + (gm0 & 2047)] = pk;
            }
        }
    }
}

// ---------------- output projection: 128x64 tiles, double-buffered ----------------
// XCD swizzle: grid (16,32); xcd = x&7, j = (x>>3) + 2y in [0,64):
// bm = (x&7)*4 + (j&3), bn = j>>2 -> per-XCD 1MB A + 2MB W, L2-resident.
__global__ __launch_bounds__(256) void out_gemm_kernel(
    const unsigned short* __restrict__ Obf, const unsigned short* __restrict__ Wot,
    const float* __restrict__ bo, float* __restrict__ out)
{
    __shared__ __align__(16) unsigned short As[2*4096];   // 16 KB
    __shared__ __align__(16) unsigned short Bs[2*2048];   // 8 KB

    const int t = threadIdx.x;
    const int w = t >> 6, l = t & 63;
    const int quad = l >> 4, col = l & 15;

    const int j  = (blockIdx.x >> 3) + 2 * blockIdx.y;
    const int bm = ((blockIdx.x & 7) * 4 + (j & 3)) * 128;
    const int bn = (j >> 2) * 64;

    const int wr = (w >> 1) * 64, wc = (w & 1) * 32;

    const int r0 = t >> 2, o0 = (t & 3) * 8;
    const unsigned short* Ar0 = Obf + (size_t)(bm + r0) * DDIM + o0;
    const unsigned short* Ar1 = Obf + (size_t)(bm + 64 + r0) * DDIM + o0;
    const unsigned short* Br  = Wot + (size_t)(bn + r0) * DDIM + o0;

    floatx4 acc[4][2] = {};

    GLD16(Ar0, As + t*8);
    GLD16(Ar1, As + (t + 256)*8);
    GLD16(Br,  Bs + t*8);

    for (int kt = 0; kt < DDIM; kt += 32) {
        const int cur = (kt >> 5) & 1;
        unsigned short* Asn = As + (cur ^ 1) * 4096;
        unsigned short* Bsn = Bs + (cur ^ 1) * 2048;
        __syncthreads();
        if (kt + 32 < DDIM) {
            GLD16(Ar0 + kt + 32, Asn + t*8);
            GLD16(Ar1 + kt + 32, Asn + (t + 256)*8);
            GLD16(Br  + kt + 32, Bsn + t*8);
        }
        const unsigned short* Asc = As + cur*4096;
        const unsigned short* Bsc = Bs + cur*2048;
        short8 af[4], bfr[2];
        #pragma unroll
        for (int i = 0; i < 4; ++i)
            af[i] = *(const short8*)&Asc[(wr + i*16 + col)*32 + quad*8];
        #pragma unroll
        for (int j2 = 0; j2 < 2; ++j2)
            bfr[j2] = *(const short8*)&Bsc[(wc + j2*16 + col)*32 + quad*8];
        #pragma unroll
        for (int i = 0; i < 4; ++i)
            #pragma unroll
            for (int j2 = 0; j2 < 2; ++j2)
                acc[i][j2] = __builtin_amdgcn_mfma_f32_16x16x32_bf16(
                    bfr[j2], af[i], acc[i][j2], 0, 0, 0);
    }

    float4 bias4[2];
    #pragma unroll
    for (int j2 = 0; j2 < 2; ++j2)
        bias4[j2] = *(const float4*)&bo[bn + wc + j2*16 + quad*4];
    #pragma unroll
    for (int i = 0; i < 4; ++i) {
        const int m = bm + wr + i*16 + col;
        float* rowp = out + (size_t)m * DDIM;
        #pragma unroll
        for (int j2 = 0; j2 < 2; ++j2) {
            float4 o;
            o.x = acc[i][j2][0] + bias4[j2].x;
            o.y = acc[i][j2][1] + bias4[j2].y;
            o.z = acc[i][j2][2] + bias4[j2].z;
            o.w = acc[i][j2][3] + bias4[j2].w;
            *(float4*)&rowp[bn + wc + j2*16 + quad*4] = o;
        }
    }
}

// ---------------- MFMA flash attention: 8-wave uniform blocks, key-split ----------------
// Block = (b,h, pair p), 512 threads (8 waves). Tile 31-p then tile p; keys
// split it = w, w+8, ... -> exactly 33 chunks/block, 512 blocks = 2/CU =
// 16 waves/CU (4/SIMD at ~116 VGPR). Per-wave loop identical to R14 (16
// short8 loads/chunk in one burst; K/V global->VGPR, L2-resident via XCD
// head pinning). In-register P via key permutation. Combine: 3-level LDS
// tree, two sub-rounds at level 1 to keep LDS at 34KB.
__global__ __launch_bounds__(512, 4) void attn_mfma_kernel(
    const unsigned short* __restrict__ Qbf, const unsigned short* __restrict__ Kbf,
    const unsigned short* __restrict__ vT, unsigned short* __restrict__ Obf)
{
    __shared__ float ls[2][4*64];                 //  2 KB
    __shared__ __align__(16) floatx4 os[2][1024]; // 32 KB

    const int t = threadIdx.x;
    const int w = t >> 6, l = t & 63;
    const int quad = l >> 4, col = l & 15;

    // decode: xcd = lin&7; j = lin>>3 in [0,64): rem = j&3 -> (b, h-half),
    // p = j>>2 in [0,16) -> tile pair (31-p, p). h = (lin&7) + 8*(rem>>1).
    const int lin = blockIdx.x;
    const int jj  = lin >> 3, rem = jj & 3;
    const int p   = jj >> 2;
    const int b   = rem & 1;
    const int h   = (lin & 7) + 8 * (rem >> 1);

    const size_t hoff = (size_t)h * HD;
    const size_t bS   = (size_t)b * SDIM;
    const size_t bD   = (size_t)b * DDIM;

    // per-lane permuted K-row within a 32-key pair: (col>>2)*8 + (col&3)
    const int rowp = ((col >> 2) << 3) | (col & 3);
    const unsigned short* kb0 = Kbf + bS * DDIM + hoff + quad*8;
    const unsigned short* vb0 = vT + (bD + hoff + col) * SDIM + quad*8;

#define DEPOSIT(slot)                                                        \
    do {                                                                     \
        _Pragma("unroll")                                                    \
        for (int n = 0; n < 4; ++n)                                          \
            _Pragma("unroll")                                                \
            for (int m = 0; m < 4; ++m)                                      \
                os[slot][(n*4 + m)*64 + l] = o[n][m];                        \
        _Pragma("unroll")                                                    \
        for (int m = 0; m < 4; ++m)                                          \
            ls[slot][m*64 + l] = lrun[m];                                    \
    } while (0)

#define ACCUM(slot)                                                          \
    do {                                                                     \
        _Pragma("unroll")                                                    \
        for (int n = 0; n < 4; ++n)                                          \
            _Pragma("unroll")                                                \
            for (int m = 0; m < 4; ++m)                                      \
                o[n][m] += os[slot][(n*4 + m)*64 + l];                       \
        _Pragma("unroll")                                                    \
        for (int m = 0; m < 4; ++m)                                          \
            lrun[m] += ls[slot][m*64 + l];                                   \
    } while (0)

    #pragma unroll 1
    for (int ph = 0; ph < 2; ++ph) {
        const int qT = ph ? p : (31 - p);
        const int qb = qT * 64;

        // persistent Q fragments: B-frag  Q[qb+m*16+col][hoff+hf*32+quad*8+j]
        short8 qf[4][2];
        #pragma unroll
        for (int m = 0; m < 4; ++m)
            #pragma unroll
            for (int hf = 0; hf < 2; ++hf)
                qf[m][hf] = *(const short8*)
                    &Qbf[(bS + qb + m*16 + col) * DDIM + hoff + hf*32 + quad*8];

        floatx4 o[4][4] = {};          // o[n][m]: O^T tile (hd n, qrow m)
        float lrun[4] = {0.f, 0.f, 0.f, 0.f};

        #pragma unroll 1
        for (int it = w; it <= qT; it += 8) {
            const int ktb = it * 64;
            const bool diag = (it == qT);

            // K fragments: A[row=l&15 -> key ktb+c*32+perm][hd hf*32+quad*8+j]
            short8 kf[2][2][2];
            #pragma unroll
            for (int c = 0; c < 2; ++c)
                #pragma unroll
                for (int tt = 0; tt < 2; ++tt) {
                    const size_t row = (size_t)(ktb + c*32 + tt*4 + rowp);
                    kf[c][tt][0] = *(const short8*)&kb0[row * DDIM];
                    kf[c][tt][1] = *(const short8*)&kb0[row * DDIM + 32];
                }
            // V fragments: A[row=hd n*16+(l&15)][key ktb+c*32+quad*8+j]
            short8 vf[4][2];
            #pragma unroll
            for (int n = 0; n < 4; ++n)
                #pragma unroll
                for (int c = 0; c < 2; ++c)
                    vf[n][c] = *(const short8*)
                        &vb0[(size_t)(n*16) * SDIM + ktb + c*32];

            #pragma unroll
            for (int m = 0; m < 4; ++m) {
                #pragma unroll
                for (int c = 0; c < 2; ++c) {
                    if (diag && (c*32 > m*16 + 15)) continue;   // fully masked
                    const bool needm = diag && (c*32 + 31 > m*16);

                    floatx4 s0 = {}, s1 = {};
                    __builtin_amdgcn_s_setprio(1);
                    s0 = __builtin_amdgcn_mfma_f32_16x16x32_bf16(kf[c][0][0], qf[m][0], s0, 0, 0, 0);
                    s0 = __builtin_amdgcn_mfma_f32_16x16x32_bf16(kf[c][0][1], qf[m][1], s0, 0, 0, 0);
                    s1 = __builtin_amdgcn_mfma_f32_16x16x32_bf16(kf[c][1][0], qf[m][0], s1, 0, 0, 0);
                    s1 = __builtin_amdgcn_mfma_f32_16x16x32_bf16(kf[c][1][1], qf[m][1], s1, 0, 0, 0);
                    __builtin_amdgcn_s_setprio(0);

                    // lane's keys: tile0 -> c*32+quad*8+r, tile1 -> +4
                    float p0[4], p1[4];
                    const int qrow = m*16 + col;
                    const int kls  = c*32 + quad*8;
                    #pragma unroll
                    for (int rr = 0; rr < 4; ++rr) {
                        p0[rr] = (needm && (kls + rr     > qrow)) ? 0.0f : exp2f(s0[rr]);
                        p1[rr] = (needm && (kls + 4 + rr > qrow)) ? 0.0f : exp2f(s1[rr]);
                    }
                    lrun[m] += ((p0[0]+p0[1]) + (p0[2]+p0[3]))
                             + ((p1[0]+p1[1]) + (p1[2]+p1[3]));

                    union { short8 v; unsigned int u[4]; } pf;
                    pf.u[0] = pack2bf(p0[0], p0[1]);
                    pf.u[1] = pack2bf(p0[2], p0[3]);
                    pf.u[2] = pack2bf(p1[0], p1[1]);
                    pf.u[3] = pack2bf(p1[2], p1[3]);

                    __builtin_amdgcn_s_setprio(1);
                    #pragma unroll
                    for (int n = 0; n < 4; ++n)
                        o[n][m] = __builtin_amdgcn_mfma_f32_16x16x32_bf16(
                            vf[n][c], pf.v, o[n][m], 0, 0, 0);
                    __builtin_amdgcn_s_setprio(0);
                }
            }
        }

        // ---- combine: 8 -> 4 (two sub-rounds) -> 2 -> 1, wave 0 stores ----
        if (w == 4 || w == 5) DEPOSIT(w - 4);
        __syncthreads();
        if (w == 0 || w == 1) ACCUM(w);
        __syncthreads();
        if (w == 6 || w == 7) DEPOSIT(w - 6);
        __syncthreads();
        if (w == 2 || w == 3) ACCUM(w - 2);
        __syncthreads();
        if (w == 2 || w == 3) DEPOSIT(w - 2);
        __syncthreads();
        if (w == 0 || w == 1) ACCUM(w);
        __syncthreads();
        if (w == 1) DEPOSIT(0);
        __syncthreads();
        if (w == 0) {
            #pragma unroll
            for (int m = 0; m < 4; ++m) {
                float lt = lrun[m] + ls[0][m*64 + l];
                lt += __shfl_xor(lt, 16);
                lt += __shfl_xor(lt, 32);
                const float inv = 1.0f / lt;
                #pragma unroll
                for (int n = 0; n < 4; ++n) {
                    const floatx4 ov = o[n][m] + os[0][(n*4 + m)*64 + l];
                    uint2 pk;
                    pk.x = pack2bf(ov[0] * inv, ov[1] * inv);
                    pk.y = pack2bf(ov[2] * inv, ov[3] * inv);
                    *(uint2*)&Obf[(bS + qb + m*16 + col) * DDIM
                                  + hoff + n*16 + quad*4] = pk;
                }
            }
        }
        __syncthreads();   // LDS reused by next phase
    }
#undef DEPOSIT
#undef ACCUM
}

extern "C" void kernel_launch(void* const* d_in, const int* in_sizes, int n_in,
                              void* d_out, int out_size, void* d_ws, size_t ws_size,
                              hipStream_t stream) {
    const float* x  = (const float*)d_in[0];
    const float* y  = (const float*)d_in[1];
    const float* Wq = (const float*)d_in[2];
    const float* bq = (const float*)d_in[3];
    const float* Wk = (const float*)d_in[4];
    const float* bk = (const float*)d_in[5];
    const float* Wv = (const float*)d_in[6];
    const float* bv = (const float*)d_in[7];
    const float* Wo = (const float*)d_in[8];
    const float* bo = (const float*)d_in[9];
    float* out = (float*)d_out;

    const size_t mat  = (size_t)MDIM * DDIM;
    const size_t wmat = (size_t)DDIM * DDIM;
    unsigned short* p = (unsigned short*)d_ws;
    unsigned short* xbf = p;            p += mat;
    unsigned short* ybf = p;            p += mat;
    unsigned short* Wqt = p;            p += wmat;
    unsigned short* Wkt = p;            p += wmat;
    unsigned short* Wvt = p;            p += wmat;
    unsigned short* Wot = p;            p += wmat;
    unsigned short* Qbf = p;            p += mat;
    unsigned short* Kbf = p;            p += mat;
    unsigned short* vT  = p;            p += mat;
    unsigned short* Obf = p;            p += mat;

    hipLaunchKernelGGL(prep_kernel, dim3(MDIM*DDIM/8/256, 1, 6), dim3(256),
                       0, stream, x, y, Wq, Wk, Wv, Wo,
                       xbf, ybf, Wqt, Wkt, Wvt, Wot);

    hipLaunchKernelGGL(qkv_gemm_kernel, dim3(DDIM/128, MDIM/128, 3), dim3(256),
                       0, stream, xbf, ybf, Wqt, Wkt, Wvt, bq, bk, bv,
                       Qbf, Kbf, vT);

    hipLaunchKernelGGL(attn_mfma_kernel, dim3(512), dim3(512),
                       0, stream, Qbf, Kbf, vT, Obf);

    hipLaunchKernelGGL(out_gemm_kernel, dim3(DDIM/64, MDIM/128), dim3(256),
                       0, stream, Obf, Wot, bo, out);
}

// Round 7
// 269.059 us; speedup vs baseline: 1.2261x; 1.2261x over previous
//
#include <hip/hip_runtime.h>
#include <hip/hip_bf16.h>

// CrossAttention  B=2, S=2048, D=1024, H=16, HD=64
// R17: R16 post-mortem -- launch_bounds(512,4) forced <=128 regs/wave while
// the decomposition needs ~180 (64 acc AGPR alone) -> VGPR squeezed to 64,
// 700MB spill I/O. TLP is hard-capped at 2 waves/SIMD; R17 buys ILP instead:
// R14's exact structure + K-only register double-buffer done with TEXTUAL
// MACROS (R13's spill was lambdas taking local arrays as params -> arrays
// become addressable -> scratch; macros keep all indices compile-time).
// Prefetch LOADK(kfB, it+4) issues before COMPUTE(kfA) so the ~250cyc L2
// latency of the next chunk's K hides under this chunk's MFMA+softmax.
// Budget: ~160 VGPR + 64 AGPR = 224 <= 256 -> still 2 waves/SIMD, no spill.
// prep/qkv/out kernels unchanged.

#define BDIM 2
#define SDIM 2048
#define DDIM 1024
#define HDIM 16
#define HD   64
#define MDIM (BDIM*SDIM)   // 4096
// folded into Q at projection: (1/8) * log2(e)
#define C2 0.18033688011112042f

using short8  = __attribute__((ext_vector_type(8))) short;
using floatx4 = __attribute__((ext_vector_type(4))) float;

static __device__ __forceinline__ unsigned short f2bf(float x) {
    union { float f; unsigned int u; } c; c.f = x;
    unsigned int r = (c.u + 0x7fffu + ((c.u >> 16) & 1u)) >> 16;
    return (unsigned short)r;
}

// pack two fp32 -> (bf16(b)<<16)|bf16(a), round-half-up
static __device__ __forceinline__ unsigned int pack2bf(float a, float b) {
    union { float f; unsigned int u; } ua, ub;
    ua.f = a; ub.f = b;
    return __builtin_amdgcn_perm(ub.u + 0x8000u, ua.u + 0x8000u, 0x07060302u);
}

#define GLD16(g, l) __builtin_amdgcn_global_load_lds(                        \
    (const __attribute__((address_space(1))) void*)(g),                      \
    (__attribute__((address_space(3))) void*)(l), 16, 0, 0)

// ---------------- fused prep: cast x/y -> bf16 (z=0,1), wtrans (z=2..5) ----------------
__global__ __launch_bounds__(256) void prep_kernel(
    const float* __restrict__ X, const float* __restrict__ Y,
    const float* __restrict__ W0, const float* __restrict__ W1,
    const float* __restrict__ W2, const float* __restrict__ W3,
    unsigned short* __restrict__ Xo, unsigned short* __restrict__ Yo,
    unsigned short* __restrict__ T0, unsigned short* __restrict__ T1,
    unsigned short* __restrict__ T2, unsigned short* __restrict__ T3)
{
    __shared__ float tile[64][68];
    const int z = blockIdx.z;
    const int t = threadIdx.x;
    if (z < 2) {
        const float* A    = z ? Y : X;
        unsigned short* O = z ? Yo : Xo;
        const int idx = blockIdx.x * 256 + t;
        const float4 a = ((const float4*)A)[idx*2];
        const float4 b = ((const float4*)A)[idx*2 + 1];
        ushort4 lo, hi;
        lo.x = f2bf(a.x); lo.y = f2bf(a.y); lo.z = f2bf(a.z); lo.w = f2bf(a.w);
        hi.x = f2bf(b.x); hi.y = f2bf(b.y); hi.z = f2bf(b.z); hi.w = f2bf(b.w);
        ((ushort4*)O)[idx*2]     = lo;
        ((ushort4*)O)[idx*2 + 1] = hi;
        return;
    }
    if (blockIdx.x >= 256) return;
    const int zz = z - 2;
    const float* W    = (zz == 0) ? W0 : (zz == 1) ? W1 : (zz == 2) ? W2 : W3;
    unsigned short* T = (zz == 0) ? T0 : (zz == 1) ? T1 : (zz == 2) ? T2 : T3;
    const int k0 = (blockIdx.x & 15) * 64, n0 = (blockIdx.x >> 4) * 64;
    #pragma unroll
    for (int i = 0; i < 4; ++i) {
        const int idx = t + i*256;
        const int kr = idx >> 4, c4 = idx & 15;
        float4 v = *(const float4*)&W[(size_t)(k0 + kr) * DDIM + n0 + c4*4];
        tile[kr][c4*4+0] = v.x; tile[kr][c4*4+1] = v.y;
        tile[kr][c4*4+2] = v.z; tile[kr][c4*4+3] = v.w;
    }
    __syncthreads();
    #pragma unroll
    for (int i = 0; i < 4; ++i) {
        const int idx = t + i*256;
        const int nr = idx >> 4, kc = idx & 15;
        ushort4 o;
        o.x = f2bf(tile[kc*4+0][nr]); o.y = f2bf(tile[kc*4+1][nr]);
        o.z = f2bf(tile[kc*4+2][nr]); o.w = f2bf(tile[kc*4+3][nr]);
        *(ushort4*)&T[(size_t)(n0 + nr) * DDIM + k0 + kc*4] = o;
    }
}

// ---------------- 128x128 bf16 MFMA GEMM core, LDS double-buffered ----------------
template <bool SWAP>
__device__ __forceinline__ void gemm128_core(
    const unsigned short* __restrict__ A, const unsigned short* __restrict__ Bt,
    int bm, int bn, unsigned short* As, unsigned short* Bs, floatx4 acc[4][4])
{
    const int t = threadIdx.x;
    const int w = t >> 6, l = t & 63;
    const int quad = l >> 4, col = l & 15;
    const int wr = (w >> 1) * 64, wc = (w & 1) * 64;

    const int c1 = t + 256;
    const int r0 = t >> 2,  o0 = (t & 3) * 8;
    const int r1 = c1 >> 2, o1 = (c1 & 3) * 8;

    const unsigned short* Ar0 = A  + (size_t)(bm + r0) * DDIM + o0;
    const unsigned short* Ar1 = A  + (size_t)(bm + r1) * DDIM + o1;
    const unsigned short* Br0 = Bt + (size_t)(bn + r0) * DDIM + o0;
    const unsigned short* Br1 = Bt + (size_t)(bn + r1) * DDIM + o1;

    GLD16(Ar0, As + t*8);
    GLD16(Ar1, As + c1*8);
    GLD16(Br0, Bs + t*8);
    GLD16(Br1, Bs + c1*8);

    for (int kt = 0; kt < DDIM; kt += 32) {
        const int cur = (kt >> 5) & 1;
        unsigned short* Asn = As + (cur ^ 1) * 4096;
        unsigned short* Bsn = Bs + (cur ^ 1) * 4096;
        __syncthreads();
        if (kt + 32 < DDIM) {
            GLD16(Ar0 + kt + 32, Asn + t*8);
            GLD16(Ar1 + kt + 32, Asn + c1*8);
            GLD16(Br0 + kt + 32, Bsn + t*8);
            GLD16(Br1 + kt + 32, Bsn + c1*8);
        }
        const unsigned short* Asc = As + cur*4096;
        const unsigned short* Bsc = Bs + cur*4096;
        short8 af[4], bfr[4];
        #pragma unroll
        for (int i = 0; i < 4; ++i)
            af[i] = *(const short8*)&Asc[(wr + i*16 + col)*32 + quad*8];
        #pragma unroll
        for (int j = 0; j < 4; ++j)
            bfr[j] = *(const short8*)&Bsc[(wc + j*16 + col)*32 + quad*8];
        #pragma unroll
        for (int i = 0; i < 4; ++i)
            #pragma unroll
            for (int j = 0; j < 4; ++j)
                acc[i][j] = SWAP
                    ? __builtin_amdgcn_mfma_f32_16x16x32_bf16(bfr[j], af[i], acc[i][j], 0, 0, 0)
                    : __builtin_amdgcn_mfma_f32_16x16x32_bf16(af[i], bfr[j], acc[i][j], 0, 0, 0);
    }
}

// ---------------- fused Q/K/V projection (grid.z = 0/1/2) ----------------
// XCD swizzle: raw (x,y) with x in [0,8): xcd = x (lin%8). bm = x*4+(y&3),
// bn = y>>2 -> per-XCD A set = 4 tiles (1MB), W = 2MB: both L2-resident.
__global__ __launch_bounds__(256) void qkv_gemm_kernel(
    const unsigned short* __restrict__ xbf, const unsigned short* __restrict__ ybf,
    const unsigned short* __restrict__ Wqt, const unsigned short* __restrict__ Wkt,
    const unsigned short* __restrict__ Wvt,
    const float* __restrict__ bq, const float* __restrict__ bk,
    const float* __restrict__ bv,
    unsigned short* __restrict__ Qbf, unsigned short* __restrict__ Kbf,
    unsigned short* __restrict__ vT)
{
    __shared__ __align__(16) unsigned short As[2*4096];   // 16 KB
    __shared__ __align__(16) unsigned short Bs[2*4096];   // 16 KB

    const int z = blockIdx.z;
    const unsigned short* A  = (z == 0) ? xbf : ybf;
    const unsigned short* Wt = (z == 0) ? Wqt : (z == 1) ? Wkt : Wvt;
    const float* bp          = (z == 0) ? bq  : (z == 1) ? bk  : bv;

    // XCD-aware remap (grid (8,32,z)): xcd = blockIdx.x
    const int bm = (blockIdx.x * 4 + (blockIdx.y & 3)) * 128;
    const int bn = (blockIdx.y >> 2) * 128;

    const int t = threadIdx.x;
    const int w = t >> 6, l = t & 63;
    const int quad = l >> 4, col = l & 15;
    const int wr = (w >> 1) * 64, wc = (w & 1) * 64;

    floatx4 acc[4][4] = {};

    if (z < 2) {
        gemm128_core<true>(A, Wt, bm, bn, As, Bs, acc);
        unsigned short* O = (z == 0) ? Qbf : Kbf;
        const float sc = (z == 0) ? C2 : 1.0f;
        float4 bias4[4];
        #pragma unroll
        for (int j = 0; j < 4; ++j)
            bias4[j] = *(const float4*)&bp[bn + wc + j*16 + quad*4];
        #pragma unroll
        for (int i = 0; i < 4; ++i) {
            const int m = bm + wr + i*16 + col;
            unsigned short* rowp = O + (size_t)m * DDIM;
            #pragma unroll
            for (int j = 0; j < 4; ++j) {
                const float v0 = (acc[i][j][0] + bias4[j].x) * sc;
                const float v1 = (acc[i][j][1] + bias4[j].y) * sc;
                const float v2 = (acc[i][j][2] + bias4[j].z) * sc;
                const float v3 = (acc[i][j][3] + bias4[j].w) * sc;
                uint2 pk;
                pk.x = pack2bf(v0, v1);
                pk.y = pack2bf(v2, v3);
                *(uint2*)&rowp[bn + wc + j*16 + quad*4] = pk;
            }
        }
    } else {
        gemm128_core<false>(A, Wt, bm, bn, As, Bs, acc);
        #pragma unroll
        for (int j = 0; j < 4; ++j) {
            const int gn = bn + wc + j*16 + col;
            const float bias = bp[gn];
            #pragma unroll
            for (int i = 0; i < 4; ++i) {
                const int gm0 = bm + wr + i*16 + quad*4;
                uint2 pk;
                pk.x = pack2bf(acc[i][j][0] + bias, acc[i][j][1] + bias);
                pk.y = pack2bf(acc[i][j][2] + bias, acc[i][j][3] + bias);
                *(uint2*)&vT[((size_t)((gm0 >> 11) * DDIM + gn)) * SDIM + (gm0 & 2047)] = pk;
            }
        }
    }
}

// ---------------- output projection: 128x64 tiles, double-buffered ----------------
// XCD swizzle: grid (16,32); xcd = x&7, j = (x>>3) + 2y in [0,64):
// bm = (x&7)*4 + (j&3), bn = j>>2 -> per-XCD 1MB A + 2MB W, L2-resident.
__global__ __launch_bounds__(256) void out_gemm_kernel(
    const unsigned short* __restrict__ Obf, const unsigned short* __restrict__ Wot,
    const float* __restrict__ bo, float* __restrict__ out)
{
    __shared__ __align__(16) unsigned short As[2*4096];   // 16 KB
    __shared__ __align__(16) unsigned short Bs[2*2048];   // 8 KB

    const int t = threadIdx.x;
    const int w = t >> 6, l = t & 63;
    const int quad = l >> 4, col = l & 15;

    const int j  = (blockIdx.x >> 3) + 2 * blockIdx.y;
    const int bm = ((blockIdx.x & 7) * 4 + (j & 3)) * 128;
    const int bn = (j >> 2) * 64;

    const int wr = (w >> 1) * 64, wc = (w & 1) * 32;

    const int r0 = t >> 2, o0 = (t & 3) * 8;
    const unsigned short* Ar0 = Obf + (size_t)(bm + r0) * DDIM + o0;
    const unsigned short* Ar1 = Obf + (size_t)(bm + 64 + r0) * DDIM + o0;
    const unsigned short* Br  = Wot + (size_t)(bn + r0) * DDIM + o0;

    floatx4 acc[4][2] = {};

    GLD16(Ar0, As + t*8);
    GLD16(Ar1, As + (t + 256)*8);
    GLD16(Br,  Bs + t*8);

    for (int kt = 0; kt < DDIM; kt += 32) {
        const int cur = (kt >> 5) & 1;
        unsigned short* Asn = As + (cur ^ 1) * 4096;
        unsigned short* Bsn = Bs + (cur ^ 1) * 2048;
        __syncthreads();
        if (kt + 32 < DDIM) {
            GLD16(Ar0 + kt + 32, Asn + t*8);
            GLD16(Ar1 + kt + 32, Asn + (t + 256)*8);
            GLD16(Br  + kt + 32, Bsn + t*8);
        }
        const unsigned short* Asc = As + cur*4096;
        const unsigned short* Bsc = Bs + cur*2048;
        short8 af[4], bfr[2];
        #pragma unroll
        for (int i = 0; i < 4; ++i)
            af[i] = *(const short8*)&Asc[(wr + i*16 + col)*32 + quad*8];
        #pragma unroll
        for (int j2 = 0; j2 < 2; ++j2)
            bfr[j2] = *(const short8*)&Bsc[(wc + j2*16 + col)*32 + quad*8];
        #pragma unroll
        for (int i = 0; i < 4; ++i)
            #pragma unroll
            for (int j2 = 0; j2 < 2; ++j2)
                acc[i][j2] = __builtin_amdgcn_mfma_f32_16x16x32_bf16(
                    bfr[j2], af[i], acc[i][j2], 0, 0, 0);
    }

    float4 bias4[2];
    #pragma unroll
    for (int j2 = 0; j2 < 2; ++j2)
        bias4[j2] = *(const float4*)&bo[bn + wc + j2*16 + quad*4];
    #pragma unroll
    for (int i = 0; i < 4; ++i) {
        const int m = bm + wr + i*16 + col;
        float* rowp = out + (size_t)m * DDIM;
        #pragma unroll
        for (int j2 = 0; j2 < 2; ++j2) {
            float4 o;
            o.x = acc[i][j2][0] + bias4[j2].x;
            o.y = acc[i][j2][1] + bias4[j2].y;
            o.z = acc[i][j2][2] + bias4[j2].z;
            o.w = acc[i][j2][3] + bias4[j2].w;
            *(float4*)&rowp[bn + wc + j2*16 + quad*4] = o;
        }
    }
}

// ---------------- MFMA flash attention: uniform 2-tile blocks, K dbuf ----------------
// Block = (b,h, pair p): q-tile 31-p then q-tile p. 33 K-chunks/block, 512
// blocks = 2/CU, flat load. 4 waves split chunks round-robin. K/V
// global->VGPR (L2-resident, XCD-pinned head). K register double-buffered
// via textual macros (no lambdas/arrays-as-params -> no scratch): prefetch
// LOADK(next) issues before COMPUTE(cur). In-register P via key permutation.
// Per-tile 3-barrier (O,l) combine through LDS.
__global__ __launch_bounds__(256, 2) void attn_mfma_kernel(
    const unsigned short* __restrict__ Qbf, const unsigned short* __restrict__ Kbf,
    const unsigned short* __restrict__ vT, unsigned short* __restrict__ Obf)
{
    __shared__ float ls[2][4*64];                 //  2 KB
    __shared__ __align__(16) floatx4 os[2][1024]; // 32 KB

    const int t = threadIdx.x;
    const int w = t >> 6, l = t & 63;
    const int quad = l >> 4, col = l & 15;

    // decode: xcd = lin&7; j = lin>>3 in [0,64): rem = j&3 -> (b, h-half),
    // p = j>>2 in [0,16) -> tile pair (31-p, p). h = (lin&7) + 8*(rem>>1).
    const int lin = blockIdx.x;
    const int jj  = lin >> 3, rem = jj & 3;
    const int p   = jj >> 2;
    const int b   = rem & 1;
    const int h   = (lin & 7) + 8 * (rem >> 1);

    const size_t hoff = (size_t)h * HD;
    const size_t bS   = (size_t)b * SDIM;
    const size_t bD   = (size_t)b * DDIM;

    // per-lane permuted K-row within a 32-key pair: (col>>2)*8 + (col&3)
    const int rowp = ((col >> 2) << 3) | (col & 3);
    const unsigned short* kb0 = Kbf + bS * DDIM + hoff + quad*8;
    const unsigned short* vb0 = vT + (bD + hoff + col) * SDIM + quad*8;

// K fragments for chunk ITV: A[row -> key ktb+c*32+perm][hd hf*32+quad*8+j]
#define LOADK(KF, ITV)                                                       \
    do {                                                                     \
        const int ktb_ = (ITV) * 64;                                         \
        _Pragma("unroll")                                                    \
        for (int c = 0; c < 2; ++c)                                          \
            _Pragma("unroll")                                                \
            for (int tt = 0; tt < 2; ++tt) {                                 \
                const size_t row_ = (size_t)(ktb_ + c*32 + tt*4 + rowp);     \
                KF[c][tt][0] = *(const short8*)&kb0[row_ * DDIM];            \
                KF[c][tt][1] = *(const short8*)&kb0[row_ * DDIM + 32];       \
            }                                                                \
    } while (0)

// full chunk body for chunk ITV using K regs KF (V loaded inside)
#define COMPUTE(KF, ITV)                                                     \
    do {                                                                     \
        const int ktb_ = (ITV) * 64;                                         \
        const bool diag_ = ((ITV) == qT);                                    \
        short8 vf[4][2];                                                     \
        _Pragma("unroll")                                                    \
        for (int n = 0; n < 4; ++n)                                          \
            _Pragma("unroll")                                                \
            for (int c = 0; c < 2; ++c)                                      \
                vf[n][c] = *(const short8*)                                  \
                    &vb0[(size_t)(n*16) * SDIM + ktb_ + c*32];               \
        _Pragma("unroll")                                                    \
        for (int m = 0; m < 4; ++m) {                                        \
            _Pragma("unroll")                                                \
            for (int c = 0; c < 2; ++c) {                                    \
                if (diag_ && (c*32 > m*16 + 15)) continue;                   \
                const bool needm_ = diag_ && (c*32 + 31 > m*16);             \
                floatx4 s0 = {}, s1 = {};                                    \
                __builtin_amdgcn_s_setprio(1);                               \
                s0 = __builtin_amdgcn_mfma_f32_16x16x32_bf16(KF[c][0][0], qf[m][0], s0, 0, 0, 0); \
                s0 = __builtin_amdgcn_mfma_f32_16x16x32_bf16(KF[c][0][1], qf[m][1], s0, 0, 0, 0); \
                s1 = __builtin_amdgcn_mfma_f32_16x16x32_bf16(KF[c][1][0], qf[m][0], s1, 0, 0, 0); \
                s1 = __builtin_amdgcn_mfma_f32_16x16x32_bf16(KF[c][1][1], qf[m][1], s1, 0, 0, 0); \
                __builtin_amdgcn_s_setprio(0);                               \
                float p0[4], p1[4];                                          \
                const int qrow_ = m*16 + col;                                \
                const int kls_  = c*32 + quad*8;                             \
                _Pragma("unroll")                                            \
                for (int rr = 0; rr < 4; ++rr) {                             \
                    p0[rr] = (needm_ && (kls_ + rr     > qrow_)) ? 0.0f : exp2f(s0[rr]); \
                    p1[rr] = (needm_ && (kls_ + 4 + rr > qrow_)) ? 0.0f : exp2f(s1[rr]); \
                }                                                            \
                lrun[m] += ((p0[0]+p0[1]) + (p0[2]+p0[3]))                   \
                         + ((p1[0]+p1[1]) + (p1[2]+p1[3]));                  \
                union { short8 v; unsigned int u[4]; } pf;                   \
                pf.u[0] = pack2bf(p0[0], p0[1]);                             \
                pf.u[1] = pack2bf(p0[2], p0[3]);                             \
                pf.u[2] = pack2bf(p1[0], p1[1]);                             \
                pf.u[3] = pack2bf(p1[2], p1[3]);                             \
                __builtin_amdgcn_s_setprio(1);                               \
                _Pragma("unroll")                                            \
                for (int n = 0; n < 4; ++n)                                  \
                    o[n][m] = __builtin_amdgcn_mfma_f32_16x16x32_bf16(       \
                        vf[n][c], pf.v, o[n][m], 0, 0, 0);                   \
                __builtin_amdgcn_s_setprio(0);                               \
            }                                                                \
        }                                                                    \
    } while (0)

    #pragma unroll 1
    for (int ph = 0; ph < 2; ++ph) {
        const int qT = ph ? p : (31 - p);
        const int qb = qT * 64;

        // persistent Q fragments: B-frag  Q[qb+m*16+col][hoff+hf*32+quad*8+j]
        short8 qf[4][2];
        #pragma unroll
        for (int m = 0; m < 4; ++m)
            #pragma unroll
            for (int hf = 0; hf < 2; ++hf)
                qf[m][hf] = *(const short8*)
                    &Qbf[(bS + qb + m*16 + col) * DDIM + hoff + hf*32 + quad*8];

        floatx4 o[4][4] = {};          // o[n][m]: O^T tile (hd n, qrow m)
        float lrun[4] = {0.f, 0.f, 0.f, 0.f};

        // ---- main loop: K double-buffered, manual 2x unroll, no lambdas ----
        {
            short8 kfA[2][2][2], kfB[2][2][2];
            int it = w;
            if (it <= qT) {
                LOADK(kfA, it);
                for (;;) {
                    if (it + 4 <= qT) LOADK(kfB, it + 4);
                    COMPUTE(kfA, it);
                    it += 4;
                    if (it > qT) break;
                    if (it + 4 <= qT) LOADK(kfA, it + 4);
                    COMPUTE(kfB, it);
                    it += 4;
                    if (it > qT) break;
                }
            }
        }

        // ---- cross-wave combine: (0+2),(1+3) -> (0+1), wave 0 stores ----
        if (w >= 2) {
            const int s = w - 2;
            #pragma unroll
            for (int n = 0; n < 4; ++n)
                #pragma unroll
                for (int m = 0; m < 4; ++m)
                    os[s][(n*4 + m)*64 + l] = o[n][m];
            #pragma unroll
            for (int m = 0; m < 4; ++m)
                ls[s][m*64 + l] = lrun[m];
        }
        __syncthreads();
        if (w < 2) {
            #pragma unroll
            for (int n = 0; n < 4; ++n)
                #pragma unroll
                for (int m = 0; m < 4; ++m)
                    o[n][m] += os[w][(n*4 + m)*64 + l];
            #pragma unroll
            for (int m = 0; m < 4; ++m)
                lrun[m] += ls[w][m*64 + l];
        }
        __syncthreads();
        if (w == 1) {
            #pragma unroll
            for (int n = 0; n < 4; ++n)
                #pragma unroll
                for (int m = 0; m < 4; ++m)
                    os[0][(n*4 + m)*64 + l] = o[n][m];
            #pragma unroll
            for (int m = 0; m < 4; ++m)
                ls[0][m*64 + l] = lrun[m];
        }
        __syncthreads();
        if (w == 0) {
            #pragma unroll
            for (int m = 0; m < 4; ++m) {
                float lt = lrun[m] + ls[0][m*64 + l];
                lt += __shfl_xor(lt, 16);
                lt += __shfl_xor(lt, 32);
                const float inv = 1.0f / lt;
                #pragma unroll
                for (int n = 0; n < 4; ++n) {
                    const floatx4 ov = o[n][m] + os[0][(n*4 + m)*64 + l];
                    uint2 pk;
                    pk.x = pack2bf(ov[0] * inv, ov[1] * inv);
                    pk.y = pack2bf(ov[2] * inv, ov[3] * inv);
                    *(uint2*)&Obf[(bS + qb + m*16 + col) * DDIM
                                  + hoff + n*16 + quad*4] = pk;
                }
            }
        }
        __syncthreads();   // LDS reused by next phase
    }
#undef LOADK
#undef COMPUTE
}

extern "C" void kernel_launch(void* const* d_in, const int* in_sizes, int n_in,
                              void* d_out, int out_size, void* d_ws, size_t ws_size,
                              hipStream_t stream) {
    const float* x  = (const float*)d_in[0];
    const float* y  = (const float*)d_in[1];
    const float* Wq = (const float*)d_in[2];
    const float* bq = (const float*)d_in[3];
    const float* Wk = (const float*)d_in[4];
    const float* bk = (const float*)d_in[5];
    const float* Wv = (const float*)d_in[6];
    const float* bv = (const float*)d_in[7];
    const float* Wo = (const float*)d_in[8];
    const float* bo = (const float*)d_in[9];
    float* out = (float*)d_out;

    const size_t mat  = (size_t)MDIM * DDIM;
    const size_t wmat = (size_t)DDIM * DDIM;
    unsigned short* p = (unsigned short*)d_ws;
    unsigned short* xbf = p;            p += mat;
    unsigned short* ybf = p;            p += mat;
    unsigned short* Wqt = p;            p += wmat;
    unsigned short* Wkt = p;            p += wmat;
    unsigned short* Wvt = p;            p += wmat;
    unsigned short* Wot = p;            p += wmat;
    unsigned short* Qbf = p;            p += mat;
    unsigned short* Kbf = p;            p += mat;
    unsigned short* vT  = p;            p += mat;
    unsigned short* Obf = p;            p += mat;

    hipLaunchKernelGGL(prep_kernel, dim3(MDIM*DDIM/8/256, 1, 6), dim3(256),
                       0, stream, x, y, Wq, Wk, Wv, Wo,
                       xbf, ybf, Wqt, Wkt, Wvt, Wot);

    hipLaunchKernelGGL(qkv_gemm_kernel, dim3(DDIM/128, MDIM/128, 3), dim3(256),
                       0, stream, xbf, ybf, Wqt, Wkt, Wvt, bq, bk, bv,
                       Qbf, Kbf, vT);

    hipLaunchKernelGGL(attn_mfma_kernel, dim3(512), dim3(256),
                       0, stream, Qbf, Kbf, vT, Obf);

    hipLaunchKernelGGL(out_gemm_kernel, dim3(DDIM/64, MDIM/128), dim3(256),
                       0, stream, Obf, Wot, bo, out);
}

// Round 8
// 207.156 us; speedup vs baseline: 1.5924x; 1.2988x over previous
//
#include <hip/hip_runtime.h>
#include <hip/hip_bf16.h>

// CrossAttention  B=2, S=2048, D=1024, H=16, HD=64
// R18: R17 post-mortem -- 3rd consecutive spill proves K register-dbuf
// (+32 regs on top of 180) won't compile cleanly (allocator caps arch VGPR
// at 128 w/ AGPRs in use). Register-FREE prefetch instead: global_load_lds.
// Each wave owns a private 2x8KB LDS K double-buffer. Per chunk: V loads
// (regs, consumed late), 8x GLD16 staging K(it+4) into buf^1, counted
// s_waitcnt vmcnt(16) (=K(it) staged; vmcnt(8) on last iter) + sched_barrier,
// then ds_read kf from buf. NO main-loop barriers (slots wave-private).
// Combine aliases the staging LDS (post-loop barrier separates). Everything
// else identical to R14 (uniform 2-tile blocks, key-split, in-register P).
// prep/qkv/out kernels unchanged.

#define BDIM 2
#define SDIM 2048
#define DDIM 1024
#define HDIM 16
#define HD   64
#define MDIM (BDIM*SDIM)   // 4096
// folded into Q at projection: (1/8) * log2(e)
#define C2 0.18033688011112042f

using short8  = __attribute__((ext_vector_type(8))) short;
using floatx4 = __attribute__((ext_vector_type(4))) float;

static __device__ __forceinline__ unsigned short f2bf(float x) {
    union { float f; unsigned int u; } c; c.f = x;
    unsigned int r = (c.u + 0x7fffu + ((c.u >> 16) & 1u)) >> 16;
    return (unsigned short)r;
}

// pack two fp32 -> (bf16(b)<<16)|bf16(a), round-half-up
static __device__ __forceinline__ unsigned int pack2bf(float a, float b) {
    union { float f; unsigned int u; } ua, ub;
    ua.f = a; ub.f = b;
    return __builtin_amdgcn_perm(ub.u + 0x8000u, ua.u + 0x8000u, 0x07060302u);
}

#define GLD16(g, l) __builtin_amdgcn_global_load_lds(                        \
    (const __attribute__((address_space(1))) void*)(g),                      \
    (__attribute__((address_space(3))) void*)(l), 16, 0, 0)

// ---------------- fused prep: cast x/y -> bf16 (z=0,1), wtrans (z=2..5) ----------------
__global__ __launch_bounds__(256) void prep_kernel(
    const float* __restrict__ X, const float* __restrict__ Y,
    const float* __restrict__ W0, const float* __restrict__ W1,
    const float* __restrict__ W2, const float* __restrict__ W3,
    unsigned short* __restrict__ Xo, unsigned short* __restrict__ Yo,
    unsigned short* __restrict__ T0, unsigned short* __restrict__ T1,
    unsigned short* __restrict__ T2, unsigned short* __restrict__ T3)
{
    __shared__ float tile[64][68];
    const int z = blockIdx.z;
    const int t = threadIdx.x;
    if (z < 2) {
        const float* A    = z ? Y : X;
        unsigned short* O = z ? Yo : Xo;
        const int idx = blockIdx.x * 256 + t;
        const float4 a = ((const float4*)A)[idx*2];
        const float4 b = ((const float4*)A)[idx*2 + 1];
        ushort4 lo, hi;
        lo.x = f2bf(a.x); lo.y = f2bf(a.y); lo.z = f2bf(a.z); lo.w = f2bf(a.w);
        hi.x = f2bf(b.x); hi.y = f2bf(b.y); hi.z = f2bf(b.z); hi.w = f2bf(b.w);
        ((ushort4*)O)[idx*2]     = lo;
        ((ushort4*)O)[idx*2 + 1] = hi;
        return;
    }
    if (blockIdx.x >= 256) return;
    const int zz = z - 2;
    const float* W    = (zz == 0) ? W0 : (zz == 1) ? W1 : (zz == 2) ? W2 : W3;
    unsigned short* T = (zz == 0) ? T0 : (zz == 1) ? T1 : (zz == 2) ? T2 : T3;
    const int k0 = (blockIdx.x & 15) * 64, n0 = (blockIdx.x >> 4) * 64;
    #pragma unroll
    for (int i = 0; i < 4; ++i) {
        const int idx = t + i*256;
        const int kr = idx >> 4, c4 = idx & 15;
        float4 v = *(const float4*)&W[(size_t)(k0 + kr) * DDIM + n0 + c4*4];
        tile[kr][c4*4+0] = v.x; tile[kr][c4*4+1] = v.y;
        tile[kr][c4*4+2] = v.z; tile[kr][c4*4+3] = v.w;
    }
    __syncthreads();
    #pragma unroll
    for (int i = 0; i < 4; ++i) {
        const int idx = t + i*256;
        const int nr = idx >> 4, kc = idx & 15;
        ushort4 o;
        o.x = f2bf(tile[kc*4+0][nr]); o.y = f2bf(tile[kc*4+1][nr]);
        o.z = f2bf(tile[kc*4+2][nr]); o.w = f2bf(tile[kc*4+3][nr]);
        *(ushort4*)&T[(size_t)(n0 + nr) * DDIM + k0 + kc*4] = o;
    }
}

// ---------------- 128x128 bf16 MFMA GEMM core, LDS double-buffered ----------------
template <bool SWAP>
__device__ __forceinline__ void gemm128_core(
    const unsigned short* __restrict__ A, const unsigned short* __restrict__ Bt,
    int bm, int bn, unsigned short* As, unsigned short* Bs, floatx4 acc[4][4])
{
    const int t = threadIdx.x;
    const int w = t >> 6, l = t & 63;
    const int quad = l >> 4, col = l & 15;
    const int wr = (w >> 1) * 64, wc = (w & 1) * 64;

    const int c1 = t + 256;
    const int r0 = t >> 2,  o0 = (t & 3) * 8;
    const int r1 = c1 >> 2, o1 = (c1 & 3) * 8;

    const unsigned short* Ar0 = A  + (size_t)(bm + r0) * DDIM + o0;
    const unsigned short* Ar1 = A  + (size_t)(bm + r1) * DDIM + o1;
    const unsigned short* Br0 = Bt + (size_t)(bn + r0) * DDIM + o0;
    const unsigned short* Br1 = Bt + (size_t)(bn + r1) * DDIM + o1;

    GLD16(Ar0, As + t*8);
    GLD16(Ar1, As + c1*8);
    GLD16(Br0, Bs + t*8);
    GLD16(Br1, Bs + c1*8);

    for (int kt = 0; kt < DDIM; kt += 32) {
        const int cur = (kt >> 5) & 1;
        unsigned short* Asn = As + (cur ^ 1) * 4096;
        unsigned short* Bsn = Bs + (cur ^ 1) * 4096;
        __syncthreads();
        if (kt + 32 < DDIM) {
            GLD16(Ar0 + kt + 32, Asn + t*8);
            GLD16(Ar1 + kt + 32, Asn + c1*8);
            GLD16(Br0 + kt + 32, Bsn + t*8);
            GLD16(Br1 + kt + 32, Bsn + c1*8);
        }
        const unsigned short* Asc = As + cur*4096;
        const unsigned short* Bsc = Bs + cur*4096;
        short8 af[4], bfr[4];
        #pragma unroll
        for (int i = 0; i < 4; ++i)
            af[i] = *(const short8*)&Asc[(wr + i*16 + col)*32 + quad*8];
        #pragma unroll
        for (int j = 0; j < 4; ++j)
            bfr[j] = *(const short8*)&Bsc[(wc + j*16 + col)*32 + quad*8];
        #pragma unroll
        for (int i = 0; i < 4; ++i)
            #pragma unroll
            for (int j = 0; j < 4; ++j)
                acc[i][j] = SWAP
                    ? __builtin_amdgcn_mfma_f32_16x16x32_bf16(bfr[j], af[i], acc[i][j], 0, 0, 0)
                    : __builtin_amdgcn_mfma_f32_16x16x32_bf16(af[i], bfr[j], acc[i][j], 0, 0, 0);
    }
}

// ---------------- fused Q/K/V projection (grid.z = 0/1/2) ----------------
// XCD swizzle: raw (x,y) with x in [0,8): xcd = x (lin%8). bm = x*4+(y&3),
// bn = y>>2 -> per-XCD A set = 4 tiles (1MB), W = 2MB: both L2-resident.
__global__ __launch_bounds__(256) void qkv_gemm_kernel(
    const unsigned short* __restrict__ xbf, const unsigned short* __restrict__ ybf,
    const unsigned short* __restrict__ Wqt, const unsigned short* __restrict__ Wkt,
    const unsigned short* __restrict__ Wvt,
    const float* __restrict__ bq, const float* __restrict__ bk,
    const float* __restrict__ bv,
    unsigned short* __restrict__ Qbf, unsigned short* __restrict__ Kbf,
    unsigned short* __restrict__ vT)
{
    __shared__ __align__(16) unsigned short As[2*4096];   // 16 KB
    __shared__ __align__(16) unsigned short Bs[2*4096];   // 16 KB

    const int z = blockIdx.z;
    const unsigned short* A  = (z == 0) ? xbf : ybf;
    const unsigned short* Wt = (z == 0) ? Wqt : (z == 1) ? Wkt : Wvt;
    const float* bp          = (z == 0) ? bq  : (z == 1) ? bk  : bv;

    // XCD-aware remap (grid (8,32,z)): xcd = blockIdx.x
    const int bm = (blockIdx.x * 4 + (blockIdx.y & 3)) * 128;
    const int bn = (blockIdx.y >> 2) * 128;

    const int t = threadIdx.x;
    const int w = t >> 6, l = t & 63;
    const int quad = l >> 4, col = l & 15;
    const int wr = (w >> 1) * 64, wc = (w & 1) * 64;

    floatx4 acc[4][4] = {};

    if (z < 2) {
        gemm128_core<true>(A, Wt, bm, bn, As, Bs, acc);
        unsigned short* O = (z == 0) ? Qbf : Kbf;
        const float sc = (z == 0) ? C2 : 1.0f;
        float4 bias4[4];
        #pragma unroll
        for (int j = 0; j < 4; ++j)
            bias4[j] = *(const float4*)&bp[bn + wc + j*16 + quad*4];
        #pragma unroll
        for (int i = 0; i < 4; ++i) {
            const int m = bm + wr + i*16 + col;
            unsigned short* rowp = O + (size_t)m * DDIM;
            #pragma unroll
            for (int j = 0; j < 4; ++j) {
                const float v0 = (acc[i][j][0] + bias4[j].x) * sc;
                const float v1 = (acc[i][j][1] + bias4[j].y) * sc;
                const float v2 = (acc[i][j][2] + bias4[j].z) * sc;
                const float v3 = (acc[i][j][3] + bias4[j].w) * sc;
                uint2 pk;
                pk.x = pack2bf(v0, v1);
                pk.y = pack2bf(v2, v3);
                *(uint2*)&rowp[bn + wc + j*16 + quad*4] = pk;
            }
        }
    } else {
        gemm128_core<false>(A, Wt, bm, bn, As, Bs, acc);
        #pragma unroll
        for (int j = 0; j < 4; ++j) {
            const int gn = bn + wc + j*16 + col;
            const float bias = bp[gn];
            #pragma unroll
            for (int i = 0; i < 4; ++i) {
                const int gm0 = bm + wr + i*16 + quad*4;
                uint2 pk;
                pk.x = pack2bf(acc[i][j][0] + bias, acc[i][j][1] + bias);
                pk.y = pack2bf(acc[i][j][2] + bias, acc[i][j][3] + bias);
                *(uint2*)&vT[((size_t)((gm0 >> 11) * DDIM + gn)) * SDIM + (gm0 & 2047)] = pk;
            }
        }
    }
}

// ---------------- output projection: 128x64 tiles, double-buffered ----------------
// XCD swizzle: grid (16,32); xcd = x&7, j = (x>>3) + 2y in [0,64):
// bm = (x&7)*4 + (j&3), bn = j>>2 -> per-XCD 1MB A + 2MB W, L2-resident.
__global__ __launch_bounds__(256) void out_gemm_kernel(
    const unsigned short* __restrict__ Obf, const unsigned short* __restrict__ Wot,
    const float* __restrict__ bo, float* __restrict__ out)
{
    __shared__ __align__(16) unsigned short As[2*4096];   // 16 KB
    __shared__ __align__(16) unsigned short Bs[2*2048];   // 8 KB

    const int t = threadIdx.x;
    const int w = t >> 6, l = t & 63;
    const int quad = l >> 4, col = l & 15;

    const int j  = (blockIdx.x >> 3) + 2 * blockIdx.y;
    const int bm = ((blockIdx.x & 7) * 4 + (j & 3)) * 128;
    const int bn = (j >> 2) * 64;

    const int wr = (w >> 1) * 64, wc = (w & 1) * 32;

    const int r0 = t >> 2, o0 = (t & 3) * 8;
    const unsigned short* Ar0 = Obf + (size_t)(bm + r0) * DDIM + o0;
    const unsigned short* Ar1 = Obf + (size_t)(bm + 64 + r0) * DDIM + o0;
    const unsigned short* Br  = Wot + (size_t)(bn + r0) * DDIM + o0;

    floatx4 acc[4][2] = {};

    GLD16(Ar0, As + t*8);
    GLD16(Ar1, As + (t + 256)*8);
    GLD16(Br,  Bs + t*8);

    for (int kt = 0; kt < DDIM; kt += 32) {
        const int cur = (kt >> 5) & 1;
        unsigned short* Asn = As + (cur ^ 1) * 4096;
        unsigned short* Bsn = Bs + (cur ^ 1) * 2048;
        __syncthreads();
        if (kt + 32 < DDIM) {
            GLD16(Ar0 + kt + 32, Asn + t*8);
            GLD16(Ar1 + kt + 32, Asn + (t + 256)*8);
            GLD16(Br  + kt + 32, Bsn + t*8);
        }
        const unsigned short* Asc = As + cur*4096;
        const unsigned short* Bsc = Bs + cur*2048;
        short8 af[4], bfr[2];
        #pragma unroll
        for (int i = 0; i < 4; ++i)
            af[i] = *(const short8*)&Asc[(wr + i*16 + col)*32 + quad*8];
        #pragma unroll
        for (int j2 = 0; j2 < 2; ++j2)
            bfr[j2] = *(const short8*)&Bsc[(wc + j2*16 + col)*32 + quad*8];
        #pragma unroll
        for (int i = 0; i < 4; ++i)
            #pragma unroll
            for (int j2 = 0; j2 < 2; ++j2)
                acc[i][j2] = __builtin_amdgcn_mfma_f32_16x16x32_bf16(
                    bfr[j2], af[i], acc[i][j2], 0, 0, 0);
    }

    float4 bias4[2];
    #pragma unroll
    for (int j2 = 0; j2 < 2; ++j2)
        bias4[j2] = *(const float4*)&bo[bn + wc + j2*16 + quad*4];
    #pragma unroll
    for (int i = 0; i < 4; ++i) {
        const int m = bm + wr + i*16 + col;
        float* rowp = out + (size_t)m * DDIM;
        #pragma unroll
        for (int j2 = 0; j2 < 2; ++j2) {
            float4 o;
            o.x = acc[i][j2][0] + bias4[j2].x;
            o.y = acc[i][j2][1] + bias4[j2].y;
            o.z = acc[i][j2][2] + bias4[j2].z;
            o.w = acc[i][j2][3] + bias4[j2].w;
            *(float4*)&rowp[bn + wc + j2*16 + quad*4] = o;
        }
    }
}

// ---------------- MFMA flash attention: wave-private LDS K staging ----------------
// Block = (b,h, pair p): q-tile 31-p then q-tile p. 33 K-chunks/block, 512
// blocks = 2/CU, flat load. 4 waves split chunks round-robin. K staged via
// global_load_lds into a wave-PRIVATE 2x8KB LDS double-buffer (zero VGPR
// cost): stage K(it+4) during compute(it); counted s_waitcnt vmcnt(16/8)
// before ds_read (no main-loop barriers -- slots wave-private). V loads
// global->VGPR, issued first (consumed late -> self-hiding). In-register P
// via key permutation. Combine buffers alias the staging LDS (post-loop
// barrier separates).
__global__ __launch_bounds__(256, 2) void attn_mfma_kernel(
    const unsigned short* __restrict__ Qbf, const unsigned short* __restrict__ Kbf,
    const unsigned short* __restrict__ vT, unsigned short* __restrict__ Obf)
{
    // 64 KB: K staging = 4 waves x 2 bufs x 4096 shorts (8 KB each).
    // Combine aliases: os = floatx4[2][1024] at SH[0] (32 KB),
    //                  ls = float[2][256]    at SH[16384] (2 KB).
    __shared__ __align__(16) unsigned short SH[32768];
    floatx4* os = (floatx4*)SH;
    float*   ls = (float*)(SH + 16384);

    const int t = threadIdx.x;
    const int w = t >> 6, l = t & 63;
    const int quad = l >> 4, col = l & 15;

    // decode: xcd = lin&7; j = lin>>3 in [0,64): rem = j&3 -> (b, h-half),
    // p = j>>2 in [0,16) -> tile pair (31-p, p). h = (lin&7) + 8*(rem>>1).
    const int lin = blockIdx.x;
    const int jj  = lin >> 3, rem = jj & 3;
    const int p   = jj >> 2;
    const int b   = rem & 1;
    const int h   = (lin & 7) + 8 * (rem >> 1);

    const size_t hoff = (size_t)h * HD;
    const size_t bS   = (size_t)b * SDIM;
    const size_t bD   = (size_t)b * DDIM;

    // per-lane permuted K-row within a 32-key pair: (col>>2)*8 + (col&3)
    const int rowp = ((col >> 2) << 3) | (col & 3);
    const unsigned short* vb0 = vT + (bD + hoff + col) * SDIM + quad*8;
    // staging source: lane l covers row (j*8 + l>>3), hd (l&7)*8 of a chunk
    const unsigned short* kst = Kbf + (bS + (l >> 3)) * DDIM + hoff + (l & 7)*8;
    unsigned short* slot0 = &SH[(w * 2) * 4096];   // this wave's buf0

// stage chunk ITV's K (64 keys x 64 hd, row-linear) into wave buf BUFI
#define STAGEK(BUFI, ITV)                                                    \
    do {                                                                     \
        unsigned short* dst_ = slot0 + (BUFI) * 4096;                        \
        const unsigned short* src_ = kst + (size_t)(ITV) * 64 * DDIM;        \
        _Pragma("unroll")                                                    \
        for (int js_ = 0; js_ < 8; ++js_)                                    \
            GLD16(src_ + (size_t)js_ * 8 * DDIM, dst_ + js_ * 512);          \
    } while (0)

    #pragma unroll 1
    for (int ph = 0; ph < 2; ++ph) {
        const int qT = ph ? p : (31 - p);
        const int qb = qT * 64;

        // persistent Q fragments: B-frag  Q[qb+m*16+col][hoff+hf*32+quad*8+j]
        short8 qf[4][2];
        #pragma unroll
        for (int m = 0; m < 4; ++m)
            #pragma unroll
            for (int hf = 0; hf < 2; ++hf)
                qf[m][hf] = *(const short8*)
                    &Qbf[(bS + qb + m*16 + col) * DDIM + hoff + hf*32 + quad*8];

        floatx4 o[4][4] = {};          // o[n][m]: O^T tile (hd n, qrow m)
        float lrun[4] = {0.f, 0.f, 0.f, 0.f};

        int cur = 0;
        if (w <= qT) STAGEK(0, w);     // prologue: stage first chunk

        #pragma unroll 1
        for (int it = w; it <= qT; it += 4) {
            const int ktb = it * 64;
            const bool diag = (it == qT);

            // V fragments first (consumed after QK+softmax -> self-hiding):
            // A[row=hd n*16+(l&15)][key ktb+c*32+quad*8+j]
            short8 vf[4][2];
            #pragma unroll
            for (int n = 0; n < 4; ++n)
                #pragma unroll
                for (int c = 0; c < 2; ++c)
                    vf[n][c] = *(const short8*)
                        &vb0[(size_t)(n*16) * SDIM + ktb + c*32];

            // stage next chunk, then wait for CURRENT chunk's staging:
            // outstanding after this point = 8 V (+ 8 stage-next) newest;
            // vmcnt(16/8) retires everything older -> K(it) is in LDS.
            if (it + 4 <= qT) {
                STAGEK(cur ^ 1, it + 4);
                asm volatile("s_waitcnt vmcnt(16)" ::: "memory");
            } else {
                asm volatile("s_waitcnt vmcnt(8)" ::: "memory");
            }
            __builtin_amdgcn_sched_barrier(0);

            // K fragments from LDS: row r = c*32+tt*4+rowp (permuted keys)
            const unsigned short* kslot = slot0 + cur * 4096;
            short8 kf[2][2][2];
            #pragma unroll
            for (int c = 0; c < 2; ++c)
                #pragma unroll
                for (int tt = 0; tt < 2; ++tt) {
                    const int r = c*32 + tt*4 + rowp;
                    kf[c][tt][0] = *(const short8*)&kslot[r*64 + quad*8];
                    kf[c][tt][1] = *(const short8*)&kslot[r*64 + 32 + quad*8];
                }

            #pragma unroll
            for (int m = 0; m < 4; ++m) {
                #pragma unroll
                for (int c = 0; c < 2; ++c) {
                    if (diag && (c*32 > m*16 + 15)) continue;   // fully masked
                    const bool needm = diag && (c*32 + 31 > m*16);

                    floatx4 s0 = {}, s1 = {};
                    __builtin_amdgcn_s_setprio(1);
                    s0 = __builtin_amdgcn_mfma_f32_16x16x32_bf16(kf[c][0][0], qf[m][0], s0, 0, 0, 0);
                    s0 = __builtin_amdgcn_mfma_f32_16x16x32_bf16(kf[c][0][1], qf[m][1], s0, 0, 0, 0);
                    s1 = __builtin_amdgcn_mfma_f32_16x16x32_bf16(kf[c][1][0], qf[m][0], s1, 0, 0, 0);
                    s1 = __builtin_amdgcn_mfma_f32_16x16x32_bf16(kf[c][1][1], qf[m][1], s1, 0, 0, 0);
                    __builtin_amdgcn_s_setprio(0);

                    // lane's keys: tile0 -> c*32+quad*8+r, tile1 -> +4
                    float p0[4], p1[4];
                    const int qrow = m*16 + col;
                    const int kls  = c*32 + quad*8;
                    #pragma unroll
                    for (int rr = 0; rr < 4; ++rr) {
                        p0[rr] = (needm && (kls + rr     > qrow)) ? 0.0f : exp2f(s0[rr]);
                        p1[rr] = (needm && (kls + 4 + rr > qrow)) ? 0.0f : exp2f(s1[rr]);
                    }
                    lrun[m] += ((p0[0]+p0[1]) + (p0[2]+p0[3]))
                             + ((p1[0]+p1[1]) + (p1[2]+p1[3]));

                    union { short8 v; unsigned int u[4]; } pf;
                    pf.u[0] = pack2bf(p0[0], p0[1]);
                    pf.u[1] = pack2bf(p0[2], p0[3]);
                    pf.u[2] = pack2bf(p1[0], p1[1]);
                    pf.u[3] = pack2bf(p1[2], p1[3]);

                    __builtin_amdgcn_s_setprio(1);
                    #pragma unroll
                    for (int n = 0; n < 4; ++n)
                        o[n][m] = __builtin_amdgcn_mfma_f32_16x16x32_bf16(
                            vf[n][c], pf.v, o[n][m], 0, 0, 0);
                    __builtin_amdgcn_s_setprio(0);
                }
            }
            cur ^= 1;
        }

        // all waves done reading their staging slots before combine aliases them
        __syncthreads();

        // ---- cross-wave combine: (0+2),(1+3) -> (0+1), wave 0 stores ----
        if (w >= 2) {
            const int s = w - 2;
            #pragma unroll
            for (int n = 0; n < 4; ++n)
                #pragma unroll
                for (int m = 0; m < 4; ++m)
                    os[s*1024 + (n*4 + m)*64 + l] = o[n][m];
            #pragma unroll
            for (int m = 0; m < 4; ++m)
                ls[s*256 + m*64 + l] = lrun[m];
        }
        __syncthreads();
        if (w < 2) {
            #pragma unroll
            for (int n = 0; n < 4; ++n)
                #pragma unroll
                for (int m = 0; m < 4; ++m)
                    o[n][m] += os[w*1024 + (n*4 + m)*64 + l];
            #pragma unroll
            for (int m = 0; m < 4; ++m)
                lrun[m] += ls[w*256 + m*64 + l];
        }
        __syncthreads();
        if (w == 1) {
            #pragma unroll
            for (int n = 0; n < 4; ++n)
                #pragma unroll
                for (int m = 0; m < 4; ++m)
                    os[(n*4 + m)*64 + l] = o[n][m];
            #pragma unroll
            for (int m = 0; m < 4; ++m)
                ls[m*64 + l] = lrun[m];
        }
        __syncthreads();
        if (w == 0) {
            #pragma unroll
            for (int m = 0; m < 4; ++m) {
                float lt = lrun[m] + ls[m*64 + l];
                lt += __shfl_xor(lt, 16);
                lt += __shfl_xor(lt, 32);
                const float inv = 1.0f / lt;
                #pragma unroll
                for (int n = 0; n < 4; ++n) {
                    const floatx4 ov = o[n][m] + os[(n*4 + m)*64 + l];
                    uint2 pk;
                    pk.x = pack2bf(ov[0] * inv, ov[1] * inv);
                    pk.y = pack2bf(ov[2] * inv, ov[3] * inv);
                    *(uint2*)&Obf[(bS + qb + m*16 + col) * DDIM
                                  + hoff + n*16 + quad*4] = pk;
                }
            }
        }
        __syncthreads();   // LDS reused by next phase (staging restarts)
    }
#undef STAGEK
}

extern "C" void kernel_launch(void* const* d_in, const int* in_sizes, int n_in,
                              void* d_out, int out_size, void* d_ws, size_t ws_size,
                              hipStream_t stream) {
    const float* x  = (const float*)d_in[0];
    const float* y  = (const float*)d_in[1];
    const float* Wq = (const float*)d_in[2];
    const float* bq = (const float*)d_in[3];
    const float* Wk = (const float*)d_in[4];
    const float* bk = (const float*)d_in[5];
    const float* Wv = (const float*)d_in[6];
    const float* bv = (const float*)d_in[7];
    const float* Wo = (const float*)d_in[8];
    const float* bo = (const float*)d_in[9];
    float* out = (float*)d_out;

    const size_t mat  = (size_t)MDIM * DDIM;
    const size_t wmat = (size_t)DDIM * DDIM;
    unsigned short* p = (unsigned short*)d_ws;
    unsigned short* xbf = p;            p += mat;
    unsigned short* ybf = p;            p += mat;
    unsigned short* Wqt = p;            p += wmat;
    unsigned short* Wkt = p;            p += wmat;
    unsigned short* Wvt = p;            p += wmat;
    unsigned short* Wot = p;            p += wmat;
    unsigned short* Qbf = p;            p += mat;
    unsigned short* Kbf = p;            p += mat;
    unsigned short* vT  = p;            p += mat;
    unsigned short* Obf = p;            p += mat;

    hipLaunchKernelGGL(prep_kernel, dim3(MDIM*DDIM/8/256, 1, 6), dim3(256),
                       0, stream, x, y, Wq, Wk, Wv, Wo,
                       xbf, ybf, Wqt, Wkt, Wvt, Wot);

    hipLaunchKernelGGL(qkv_gemm_kernel, dim3(DDIM/128, MDIM/128, 3), dim3(256),
                       0, stream, xbf, ybf, Wqt, Wkt, Wvt, bq, bk, bv,
                       Qbf, Kbf, vT);

    hipLaunchKernelGGL(attn_mfma_kernel, dim3(512), dim3(256),
                       0, stream, Qbf, Kbf, vT, Obf);

    hipLaunchKernelGGL(out_gemm_kernel, dim3(DDIM/64, MDIM/128), dim3(256),
                       0, stream, Obf, Wot, bo, out);
}